// Round 2
// baseline (278.439 us; speedup 1.0000x reference)
//
#include <hip/hip_runtime.h>
#include <hip/hip_bf16.h>

#define B_  64
#define I_  2048
#define D_  8
#define O_  32
#define K_  16
#define IC  8              // i's per block (register-resident W)
#define NCH (I_/IC)        // 256 chunk blocks
#define NT  512            // threads: bb(2) x il(8) x o(32)
#define OK_ (O_*K_)        // 512

// ---------------------------------------------------------------------------
// Pass kernel: for its 8 i's, for each b: u_hat -> (softmax c) -> partial s.
// W[i,o,:,:] (128 fp32) lives in registers; read once per pass from HBM.
// PASS0: c = 1/32 (softmax of zeros), vin unused.
// ATOMIC: accumulate s into part[b][e] via atomicAdd (fallback, small ws);
// else write per-chunk partials part[ch][b][e], e = k*32+o.
// ---------------------------------------------------------------------------
template<int PASS0, int ATOMIC>
__global__ __launch_bounds__(NT, 2)
void pass_kernel(const float* __restrict__ x,   // [B][I][D] fp32
                 const float* __restrict__ W,   // [I][O][D][K] fp32
                 const float* __restrict__ vin, // [B][O*K] fp32 (vsum), layout o*16+k
                 float* __restrict__ part)
{
    __shared__ __align__(16) float x_lds[B_ * IC * D_];  // [b][il*8+d] = 4096 f
    __shared__ __align__(16) float v_lds[2 * 640];       // [bb][o*20+k] padded
    __shared__ __align__(16) float red[8 * 512];         // [slot=bb*4+w][k*32+o]

    const int t  = threadIdx.x;
    const int bb = t >> 8;          // 0..1
    const int il = (t >> 5) & 7;    // 0..7
    const int o  = t & 31;          // 0..31
    const int ch = blockIdx.x;
    const int i0 = ch * IC;
    const int i  = i0 + il;

    // ---- W[i][o][d][k] -> 128 fp32 registers -------------------------------
    float Wr[D_][K_];
    {
        const float4* wp = (const float4*)(W + (size_t)(i * O_ + o) * (D_ * K_));
        float4* wf = (float4*)&Wr[0][0];
        #pragma unroll
        for (int j = 0; j < 32; ++j) wf[j] = wp[j];
    }

    // ---- stage x[:, i0:i0+8, :] into LDS (8 floats per thread) -------------
    {
        const int f = t * 8;                 // covers 4096 elements
        const int b = f >> 6;
        const int r = f & 63;
        const float* xp = x + (size_t)b * (I_ * D_) + (size_t)i0 * D_ + r;
        *(float4*)&x_lds[f]     = *(const float4*)(xp);
        *(float4*)&x_lds[f + 4] = *(const float4*)(xp + 4);
    }
    __syncthreads();

    for (int bi = 0; bi < B_ / 2; ++bi) {
        const int b = bi * 2 + bb;

        if (!PASS0) {
            // stage v for both b's of this iteration: [bb][o*20+k]
            const int bbr = t >> 8;
            const int idx = t & 255;
            const int bgl = bi * 2 + bbr;
            #pragma unroll
            for (int r2 = 0; r2 < 2; ++r2) {
                int e  = idx + r2 * 256;          // [o*16+k] order
                int o2 = e >> 4, k2 = e & 15;
                v_lds[bbr * 640 + o2 * 20 + k2] = vin[(size_t)bgl * OK_ + e];
            }
        }
        __syncthreads();

        // ---- u_hat[b, o, i, :] ------------------------------------------
        float uh[K_];
        #pragma unroll
        for (int k = 0; k < K_; ++k) uh[k] = 0.f;
        #pragma unroll
        for (int d = 0; d < D_; ++d) {
            float xv = x_lds[b * 64 + il * 8 + d];
            #pragma unroll
            for (int k = 0; k < K_; ++k) uh[k] = fmaf(xv, Wr[d][k], uh[k]);
        }

        // ---- routing coefficient c[b, o, i] ------------------------------
        float c;
        if (PASS0) {
            c = 1.0f / 32.0f;
        } else {
            float vv[K_];
            const float4* vp = (const float4*)&v_lds[bb * 640 + o * 20];
            #pragma unroll
            for (int j = 0; j < 4; ++j) ((float4*)vv)[j] = vp[j];
            float logit = 0.f;
            #pragma unroll
            for (int k = 0; k < K_; ++k) logit = fmaf(uh[k], vv[k], logit);
            // softmax over the 32 o-lanes (intra-half-wave; xor bits 0..4 only)
            float m = logit;
            #pragma unroll
            for (int off = 16; off >= 1; off >>= 1)
                m = fmaxf(m, __shfl_xor(m, off, 64));
            float ex = __expf(logit - m);
            float sm = ex;
            #pragma unroll
            for (int off = 16; off >= 1; off >>= 1)
                sm += __shfl_xor(sm, off, 64);
            c = __fdividef(ex, sm);
        }

        // ---- contribution c*u_hat, reduce over il pair within wave -------
        #pragma unroll
        for (int k = 0; k < K_; ++k) {
            float contrib = uh[k] * c;
            contrib += __shfl_xor(contrib, 32, 64);
            uh[k] = contrib;
        }
        if ((t & 63) < 32) {
            int slot = bb * 4 + (il >> 1);
            #pragma unroll
            for (int k = 0; k < K_; ++k)
                red[slot * 512 + k * 32 + o] = uh[k];   // bank = o, conflict-free
        }
        __syncthreads();

        // ---- fold 4 wave-slots, emit partial s[b] ------------------------
        {
            const int bbr = t >> 8;
            const int idx = t & 255;
            const int bgl = bi * 2 + bbr;
            #pragma unroll
            for (int r2 = 0; r2 < 2; ++r2) {
                int e = idx + r2 * 256;               // [k*32+o] order
                float s = red[(bbr * 4 + 0) * 512 + e]
                        + red[(bbr * 4 + 1) * 512 + e]
                        + red[(bbr * 4 + 2) * 512 + e]
                        + red[(bbr * 4 + 3) * 512 + e];
                if (ATOMIC) atomicAdd(&part[(size_t)bgl * OK_ + e], s);
                else        part[((size_t)ch * B_ + bgl) * OK_ + e] = s;
            }
        }
        __syncthreads();
    }
}

// ---------------------------------------------------------------------------
// reduce1: fold 256 chunk-partials down to 4 group-partials.
// part[ch][b][e] -> part2[g][b][e], g = ch/64
// ---------------------------------------------------------------------------
__global__ __launch_bounds__(512)
void reduce1(const float* __restrict__ part, float* __restrict__ part2)
{
    const int blk = blockIdx.x;        // 256
    const int g = blk & 3, b = blk >> 2;
    const int t = threadIdx.x;
    const float* p = part + ((size_t)(g * 64) * B_ + b) * OK_ + t;
    float acc = 0.f;
    #pragma unroll 8
    for (int c2 = 0; c2 < 64; ++c2) acc += p[(size_t)c2 * B_ * OK_];
    part2[((size_t)g * B_ + b) * OK_ + t] = acc;
}

// ---------------------------------------------------------------------------
// reduce2: s = sum of gcount group-partials; v = squash(s).
// out != nullptr: write fp32 output [b][o][k]. else vsum = (accum?vsum:0)+v.
// sin layout [g][b][k*32+o]; thread t -> (o=t>>4, k=t&15) so writes are [o][k].
// ---------------------------------------------------------------------------
__global__ __launch_bounds__(512)
void reduce2(const float* __restrict__ sin, int gcount,
             float* __restrict__ vsum,
             float* __restrict__ out,
             int accum)
{
    const int b = blockIdx.x;
    const int t = threadIdx.x;
    const int o = t >> 4, k = t & 15;
    const int e = k * 32 + o;
    float s = 0.f;
    for (int g = 0; g < gcount; ++g)
        s += sin[((size_t)g * B_ + b) * OK_ + e];
    float n2 = s * s;
    #pragma unroll
    for (int m = 8; m >= 1; m >>= 1) n2 += __shfl_xor(n2, m, 64);
    float scale = __fdividef(n2, 1.f + n2) * rsqrtf(n2 + 1e-7f);
    float v = scale * s;
    if (out != nullptr) {
        out[(size_t)b * OK_ + t] = v;            // [b][o][k], o=t>>4,k=t&15
    } else {
        float prev = accum ? vsum[(size_t)b * OK_ + t] : 0.f;
        vsum[(size_t)b * OK_ + t] = prev + v;
    }
}

// ---------------------------------------------------------------------------
extern "C" void kernel_launch(void* const* d_in, const int* in_sizes, int n_in,
                              void* d_out, int out_size, void* d_ws, size_t ws_size,
                              hipStream_t stream)
{
    const float* x = (const float*)d_in[0];
    const float* W = (const float*)d_in[1];
    float* out = (float*)d_out;
    char* ws = (char*)d_ws;

    const size_t partBytes  = (size_t)NCH * B_ * OK_ * 4;  // 32 MB
    const size_t part2Bytes = (size_t)4 * B_ * OK_ * 4;    // 512 KB
    const size_t vsumBytes  = (size_t)B_ * OK_ * 4;        // 128 KB

    if (ws_size >= partBytes + part2Bytes + vsumBytes) {
        float* part  = (float*)ws;
        float* part2 = (float*)(ws + partBytes);
        float* vsum  = (float*)(ws + partBytes + part2Bytes);

        // pass 0: c uniform -> v0; vsum = v0
        pass_kernel<1, 0><<<NCH, NT, 0, stream>>>(x, W, vsum, part);
        reduce1<<<256, 512, 0, stream>>>(part, part2);
        reduce2<<<B_, 512, 0, stream>>>(part2, 4, vsum, (float*)nullptr, 0);

        // pass 1: logits = u_hat . v0 -> v1; vsum = v0 + v1
        pass_kernel<0, 0><<<NCH, NT, 0, stream>>>(x, W, vsum, part);
        reduce1<<<256, 512, 0, stream>>>(part, part2);
        reduce2<<<B_, 512, 0, stream>>>(part2, 4, vsum, (float*)nullptr, 1);

        // pass 2: logits = u_hat . (v0+v1) -> v2 = output
        pass_kernel<0, 0><<<NCH, NT, 0, stream>>>(x, W, vsum, part);
        reduce1<<<256, 512, 0, stream>>>(part, part2);
        reduce2<<<B_, 512, 0, stream>>>(part2, 4, vsum, out, 0);
    } else {
        // small-workspace fallback: atomic accumulation into s-buffer
        float* sbuf = (float*)ws;                  // [B][OK] = 128 KB
        float* vsum = (float*)(ws + vsumBytes);    // [B][OK] = 128 KB

        hipMemsetAsync(sbuf, 0, vsumBytes, stream);
        pass_kernel<1, 1><<<NCH, NT, 0, stream>>>(x, W, vsum, sbuf);
        reduce2<<<B_, 512, 0, stream>>>(sbuf, 1, vsum, (float*)nullptr, 0);

        hipMemsetAsync(sbuf, 0, vsumBytes, stream);
        pass_kernel<0, 1><<<NCH, NT, 0, stream>>>(x, W, vsum, sbuf);
        reduce2<<<B_, 512, 0, stream>>>(sbuf, 1, vsum, (float*)nullptr, 1);

        hipMemsetAsync(sbuf, 0, vsumBytes, stream);
        pass_kernel<0, 1><<<NCH, NT, 0, stream>>>(x, W, vsum, sbuf);
        reduce2<<<B_, 512, 0, stream>>>(sbuf, 1, vsum, out, 0);
    }
}